// Round 14
// baseline (384.555 us; speedup 1.0000x reference)
//
#include <hip/hip_runtime.h>
#include <stdint.h>
#include <stddef.h>

typedef _Float16 half_t;
typedef _Float16 half8 __attribute__((ext_vector_type(8)));
typedef float float4v __attribute__((ext_vector_type(4)));

#define D_DIM 1792
#define B_DIM 8192

// ---------------------------------------------------------------------------
// Async global->LDS staging of ROWS*32 fp16 tile (rows along K, NT layout).
// slot = chunk ^ ((row>>1)&3): conflict-free (verified SQ_LDS_BANK_CONFLICT=0).
// ---------------------------------------------------------------------------
__device__ __forceinline__ void stage_rows(const half_t* __restrict__ src, int row0, int ld,
                                           int k0, half_t* dst, int nchunks, int tid) {
  for (int base = 0; base < nchunks; base += 256) {
    int ch  = base + tid;
    int row = ch >> 2, kc = ch & 3;
    int swz = kc ^ ((row >> 1) & 3);
    const half_t* g = src + (size_t)(row0 + row) * ld + k0 + swz * 8;
    half_t* l = dst + (size_t)(base + (tid & 192)) * 8;   // wave-uniform base; HW adds lane*16B
    __builtin_amdgcn_global_load_lds(
        (const __attribute__((address_space(1))) uint32_t*)(const void*)g,
        (__attribute__((address_space(3))) uint32_t*)(void*)l, 16, 0, 0);
  }
}

// FULL-LINE staging (128B/row = one aligned L2 line). slot = kc ^ (row&7).
// 256-thread version (tinv64 / gemm128).
__device__ __forceinline__ void stage_rows64(const half_t* __restrict__ src, int row0, int ld,
                                             int k0, half_t* dst, int nchunks, int tid) {
  for (int base = 0; base < nchunks; base += 256) {
    int ch  = base + tid;
    int row = ch >> 3, kc = ch & 7;
    int swz = kc ^ (row & 7);
    const half_t* g = src + (size_t)(row0 + row) * ld + k0 + swz * 8;
    half_t* l = dst + (size_t)(base + (tid & 192)) * 8;
    __builtin_amdgcn_global_load_lds(
        (const __attribute__((address_space(1))) uint32_t*)(const void*)g,
        (__attribute__((address_space(3))) uint32_t*)(void*)l, 16, 0, 0);
  }
}

// 512-thread full-line staging (gemm_out): 256 rows x 64 halves = 2048 chunks.
__device__ __forceinline__ void stage512(const half_t* __restrict__ src, int row0, int ld,
                                         int k0, half_t* dst, int tid) {
  for (int base = 0; base < 2048; base += 512) {
    int ch  = base + tid;
    int row = ch >> 3, kc = ch & 7;
    int swz = kc ^ (row & 7);
    const half_t* g = src + (size_t)(row0 + row) * ld + k0 + swz * 8;
    half_t* l = dst + (size_t)(base + (tid & 448)) * 8;   // wave-uniform; HW adds lane*16B
    __builtin_amdgcn_global_load_lds(
        (const __attribute__((address_space(1))) uint32_t*)(const void*)g,
        (__attribute__((address_space(3))) uint32_t*)(void*)l, 16, 0, 0);
  }
}

__device__ __forceinline__ half8 frag32(const half_t* lds, int row, int chunk) {
  int slot = chunk ^ ((row >> 1) & 3);
  return *(const half8*)(lds + row * 32 + slot * 8);
}
__device__ __forceinline__ half8 frag64(const half_t* lds, int row, int chunk) {
  int slot = chunk ^ (row & 7);
  return *(const half8*)(lds + row * 64 + slot * 8);
}

// ---------------------------------------------------------------------------
// 1. Row-normalize U -> Vh (fp16). One block per row.
// ---------------------------------------------------------------------------
__global__ __launch_bounds__(256) void normalize_rows(const float* __restrict__ U,
                                                      half_t* __restrict__ Vh) {
  int r = blockIdx.x, t = threadIdx.x;
  float v[7];
  float s = 0.f;
#pragma unroll
  for (int i = 0; i < 7; ++i) {
    v[i] = U[(size_t)r * D_DIM + t + i * 256];
    s += v[i] * v[i];
  }
#pragma unroll
  for (int m = 32; m; m >>= 1) s += __shfl_xor(s, m);
  __shared__ float red[4];
  __shared__ float tot;
  if ((t & 63) == 0) red[t >> 6] = s;
  __syncthreads();
  if (t == 0) tot = 1.0f / sqrtf(red[0] + red[1] + red[2] + red[3]);
  __syncthreads();
  float rn = tot;
#pragma unroll
  for (int i = 0; i < 7; ++i)
    Vh[(size_t)r * D_DIM + t + i * 256] = (half_t)(v[i] * rn);
}

// ---------------------------------------------------------------------------
// 2. Transpose X (fp32, D x B) -> XT (fp16, B x D). 64x64 LDS tiles.
//    NOTE: launched AFTER the WtT GEMM — XT's first 6.4MB aliases Tinv.
// ---------------------------------------------------------------------------
__global__ __launch_bounds__(256) void transpose_x(const float* __restrict__ X,
                                                   half_t* __restrict__ XT) {
  __shared__ half_t t[64][68];
  int r0 = blockIdx.x * 64, c0 = blockIdx.y * 64;
  int tid = threadIdx.x;
#pragma unroll
  for (int i = 0; i < 16; ++i) {
    int f = tid + i * 256;
    int rr = f >> 6, cc = f & 63;
    t[rr][cc] = (half_t)X[(size_t)(r0 + rr) * B_DIM + c0 + cc];
  }
  __syncthreads();
#pragma unroll
  for (int i = 0; i < 16; ++i) {
    int f = tid + i * 256;
    int cc = f >> 6, rr = f & 63;
    XT[(size_t)(c0 + cc) * D_DIM + r0 + rr] = t[rr][cc];
  }
}

// ---------------------------------------------------------------------------
// 2b. Transpose Vh (fp16, D x D) -> VhT.
// ---------------------------------------------------------------------------
__global__ __launch_bounds__(256) void transpose_h(const half_t* __restrict__ Vh,
                                                   half_t* __restrict__ VhT) {
  __shared__ half_t t[64][68];
  int r0 = blockIdx.x * 64, c0 = blockIdx.y * 64;
  int tid = threadIdx.x;
#pragma unroll
  for (int i = 0; i < 16; ++i) {
    int f = tid + i * 256;
    int rr = f >> 6, cc = f & 63;
    t[rr][cc] = Vh[(size_t)(r0 + rr) * D_DIM + c0 + cc];
  }
  __syncthreads();
#pragma unroll
  for (int i = 0; i < 16; ++i) {
    int f = tid + i * 256;
    int cc = f >> 6, rr = f & 63;
    VhT[(size_t)(c0 + cc) * D_DIM + r0 + rr] = t[rr][cc];
  }
}

// ---------------------------------------------------------------------------
// 2c. Zero the block-level zero triangles (R10-verified): Tinv strict-UPPER
//     128-blocks and TinvT strict-LOWER 128-blocks.
// ---------------------------------------------------------------------------
__global__ __launch_bounds__(256) void zero_tri(half_t* __restrict__ Tinv,
                                                half_t* __restrict__ TinvT) {
  int bc = blockIdx.x, br = blockIdx.y;
  int tid = threadIdx.x;
  half8 z = {};
  if (bc > br) {
    for (int it = 0; it < 8; ++it) {
      int ch = it * 256 + tid;
      int r = ch >> 4, c = (ch & 15) * 8;
      *(half8*)(Tinv + (size_t)(br * 128 + r) * D_DIM + bc * 128 + c) = z;
    }
  } else if (bc < br) {
    for (int it = 0; it < 8; ++it) {
      int ch = it * 256 + tid;
      int r = ch >> 4, c = (ch & 15) * 8;
      *(half8*)(TinvT + (size_t)(br * 128 + r) * D_DIM + bc * 128 + c) = z;
    }
  }
}

// ---------------------------------------------------------------------------
// 3. OUTPUT GEMM (R13-verified, 755 TF): 256x256 tile, BK=64, 8 waves,
//    counted-vmcnt(8) double-buffer; by-fast XCD ordering (FETCH ~= ideal).
//    out[m][n] = sum_k Pf[m][k] * XT[n][k]  (fp32 C).
// ---------------------------------------------------------------------------
__global__ __launch_bounds__(512) void gemm_out(const half_t* __restrict__ A,
                                                const half_t* __restrict__ B,
                                                float* __restrict__ C,
                                                int K, int lda, int ldb, int ldc) {
  int id = blockIdx.x;
  int xcd = id & 7, s = id >> 3;       // s in 0..27
  int by = s % 7;                      // M-tile (fast)
  int bx = (s / 7) * 8 + xcd;          // N-tile 0..31
  int m0 = by * 256, n0 = bx * 256;
  __shared__ half_t sA[2][256 * 64];   // 2 x 32KB
  __shared__ half_t sB[2][256 * 64];   // 2 x 32KB  => 128KB total
  int tid = threadIdx.x, lane = tid & 63;
  int wv = tid >> 6, wr = wv & 1, wc = wv >> 1;   // wave -> (M-half, N-quarter)
  int ln15 = lane & 15, quad = lane >> 4;
  float4v acc[8][4] = {};
  int NT = K / 64;                     // 28
  stage512(A, m0, lda, 0, &sA[0][0], tid);
  stage512(B, n0, ldb, 0, &sB[0][0], tid);
  stage512(A, m0, lda, 64, &sA[1][0], tid);
  stage512(B, n0, ldb, 64, &sB[1][0], tid);
  for (int t = 0; t < NT; ++t) {
    if (t + 1 < NT) asm volatile("s_waitcnt vmcnt(8)" ::: "memory");
    else            asm volatile("s_waitcnt vmcnt(0)" ::: "memory");
    __builtin_amdgcn_s_barrier();      // every wave waited for its tile-t loads
    int b = t & 1;
    const half_t* cA = &sA[b][0];
    const half_t* cB = &sB[b][0];
    half8 bf[4][2];
#pragma unroll
    for (int j = 0; j < 4; ++j)
#pragma unroll
      for (int q = 0; q < 2; ++q)
        bf[j][q] = frag64(cB, wc * 64 + j * 16 + ln15, q * 4 + quad);
#pragma unroll
    for (int i = 0; i < 8; ++i) {
      half8 a0 = frag64(cA, wr * 128 + i * 16 + ln15, quad);
      half8 a1 = frag64(cA, wr * 128 + i * 16 + ln15, 4 + quad);
#pragma unroll
      for (int j = 0; j < 4; ++j) {
        acc[i][j] = __builtin_amdgcn_mfma_f32_16x16x32_f16(a0, bf[j][0], acc[i][j], 0, 0, 0);
        acc[i][j] = __builtin_amdgcn_mfma_f32_16x16x32_f16(a1, bf[j][1], acc[i][j], 0, 0, 0);
      }
    }
    __builtin_amdgcn_s_barrier();      // all reads of buf b complete
    if (t + 2 < NT) {                  // refill buf b for tile t+2
      stage512(A, m0, lda, (t + 2) * 64, &sA[b][0], tid);
      stage512(B, n0, ldb, (t + 2) * 64, &sB[b][0], tid);
    }
  }
#pragma unroll
  for (int i = 0; i < 8; ++i)
#pragma unroll
    for (int j = 0; j < 4; ++j)
#pragma unroll
      for (int rg = 0; rg < 4; ++rg) {
        int row = m0 + wr * 128 + i * 16 + quad * 4 + rg;
        int col = n0 + wc * 64 + j * 16 + ln15;
        C[(size_t)row * ldc + col] = acc[i][j][rg];
      }
}

// ---------------------------------------------------------------------------
// 3b. D x D GEMMs (R14): 128x128 tile, BK=64, 4 waves, counted-vmcnt(8)
//     double-buffer — gemm_out's verified structure scaled down. Replaces
//     gemm64's 8-MFMA-per-barrier / drain-style loop (est ~300 TF) with
//     32 MFMA/wave per barrier-pair + next-tile loads in flight (T4).
//     Per-wave output 64x64 (acc 4x4). Grid 14x14 = 196 blocks.
//    MODE 0 (gram->T16): block skip n0>m0; Ch = (c<r) ? 2*acc : 0
//    MODE 1 (Pf build):  Ch = (r==c ? 1 : 0) - acc
//    MODE 3 (WtT):       Ch = 2*acc; Keff = n0+128 (triangular Tinv; NT=2bx+2)
// ---------------------------------------------------------------------------
template <int MODE>
__global__ __launch_bounds__(256) void gemm128(const half_t* __restrict__ A,
                                               const half_t* __restrict__ B,
                                               half_t* __restrict__ Ch,
                                               int K, int lda, int ldb, int ldc) {
  int m0 = blockIdx.y * 128, n0 = blockIdx.x * 128;
  if constexpr (MODE == 0) { if (n0 > m0) return; }
  int Keff = K;
  if constexpr (MODE == 3) Keff = n0 + 128;
  __shared__ half_t sA[2][128 * 64];   // 2 x 16KB
  __shared__ half_t sB[2][128 * 64];   // 2 x 16KB => 64KB total
  int tid = threadIdx.x, lane = tid & 63;
  int wv = tid >> 6, wr = wv & 1, wc = wv >> 1;   // 2x2 waves, 64x64 each
  int ln15 = lane & 15, quad = lane >> 4;
  float4v acc[4][4] = {};
  int NT = Keff / 64;                  // >= 2 for all launched blocks
  stage_rows64(A, m0, lda, 0, &sA[0][0], 1024, tid);
  stage_rows64(B, n0, ldb, 0, &sB[0][0], 1024, tid);
  stage_rows64(A, m0, lda, 64, &sA[1][0], 1024, tid);
  stage_rows64(B, n0, ldb, 64, &sB[1][0], 1024, tid);
  for (int t = 0; t < NT; ++t) {
    if (t + 1 < NT) asm volatile("s_waitcnt vmcnt(8)" ::: "memory");
    else            asm volatile("s_waitcnt vmcnt(0)" ::: "memory");
    __builtin_amdgcn_s_barrier();
    int b = t & 1;
    const half_t* cA = &sA[b][0];
    const half_t* cB = &sB[b][0];
    half8 bf[4][2];
#pragma unroll
    for (int j = 0; j < 4; ++j)
#pragma unroll
      for (int q = 0; q < 2; ++q)
        bf[j][q] = frag64(cB, wc * 64 + j * 16 + ln15, q * 4 + quad);
#pragma unroll
    for (int i = 0; i < 4; ++i) {
      half8 a0 = frag64(cA, wr * 64 + i * 16 + ln15, quad);
      half8 a1 = frag64(cA, wr * 64 + i * 16 + ln15, 4 + quad);
#pragma unroll
      for (int j = 0; j < 4; ++j) {
        acc[i][j] = __builtin_amdgcn_mfma_f32_16x16x32_f16(a0, bf[j][0], acc[i][j], 0, 0, 0);
        acc[i][j] = __builtin_amdgcn_mfma_f32_16x16x32_f16(a1, bf[j][1], acc[i][j], 0, 0, 0);
      }
    }
    __builtin_amdgcn_s_barrier();
    if (t + 2 < NT) {
      stage_rows64(A, m0, lda, (t + 2) * 64, &sA[b][0], 1024, tid);
      stage_rows64(B, n0, ldb, (t + 2) * 64, &sB[b][0], 1024, tid);
    }
  }
#pragma unroll
  for (int i = 0; i < 4; ++i)
#pragma unroll
    for (int j = 0; j < 4; ++j)
#pragma unroll
      for (int rg = 0; rg < 4; ++rg) {
        int row = m0 + wr * 64 + i * 16 + quad * 4 + rg;
        int col = n0 + wc * 64 + j * 16 + ln15;
        size_t idx = (size_t)row * ldc + col;
        float v = acc[i][j][rg];
        if constexpr (MODE == 0) Ch[idx] = (col < row) ? (half_t)(2.0f * v) : (half_t)0.0f;
        else if constexpr (MODE == 1) Ch[idx] = (half_t)(((row == col) ? 1.0f : 0.0f) - v);
        else Ch[idx] = (half_t)(2.0f * v);
      }
}

// ---------------------------------------------------------------------------
// 4. Invert 14 diagonal 128x128 unit-lower-triangular blocks of T (from T16).
//    One wave per column; forward substitution. Writes BOTH Tinv and TinvT
//    diagonal blocks (full 128x128 incl. zeros above diag).
// ---------------------------------------------------------------------------
__global__ __launch_bounds__(256) void diag_inv(const half_t* __restrict__ T16,
                                                half_t* __restrict__ Tinv,
                                                half_t* __restrict__ TinvT) {
  int b = blockIdx.x >> 5;        // block 0..13
  int cg = blockIdx.x & 31;       // column group
  int wave = threadIdx.x >> 6, ln = threadIdx.x & 63;
  int c = cg * 4 + wave;          // this wave's column (0..127)
  __shared__ float Ls[128][128];
  __shared__ float xw[4][128];
  for (int i = 0; i < 64; ++i) {
    int f = threadIdx.x + i * 256;
    int r = f >> 7, cc = f & 127;
    Ls[r][cc] = (cc < r) ? (float)T16[(size_t)(b * 128 + r) * D_DIM + b * 128 + cc] : 0.0f;
  }
  __syncthreads();
  float xlo = (ln == 0) ? 1.f : 0.f, xhi = 0.f;
  for (int r = c + 1; r < 128; ++r) {
    float ta = 0.f;
    int j0 = c + ln, j1 = c + 64 + ln;
    if (j0 < r) ta += Ls[r][j0] * xlo;
    if (j1 < r) ta += Ls[r][j1] * xhi;
#pragma unroll
    for (int m = 32; m; m >>= 1) ta += __shfl_xor(ta, m);
    float xr = -ta;
    if (j0 == r) xlo = xr;
    if (j1 == r) xhi = xr;
    if (ln == 0) xw[wave][r] = xr;
  }
  __syncthreads();
  for (int rr = ln; rr < 128; rr += 64) {
    float val = (rr < c) ? 0.f : ((rr == c) ? 1.f : xw[wave][rr]);
    half_t hv = (half_t)val;
    Tinv[(size_t)(b * 128 + rr) * D_DIM + b * 128 + c] = hv;
    TinvT[(size_t)(b * 128 + c) * D_DIM + b * 128 + rr] = hv;
  }
}

// ---------------------------------------------------------------------------
// 5. Doubling-chain GEMM, 64x64 tiles (R11-verified). R[m][n]=sum A[m][k]B[n][k],
//    z-batched; optional negate; O1 [m][n], optional O2 transposed [n][m].
// ---------------------------------------------------------------------------
__global__ __launch_bounds__(256) void tinv64(const half_t* __restrict__ A, int ldA, long long strA,
                                              const half_t* __restrict__ B, int ldB, long long strB,
                                              half_t* __restrict__ O1, int ldO1, long long strO1,
                                              half_t* __restrict__ O2, int ldO2, long long strO2,
                                              int K, int neg) {
  long long z = blockIdx.z;
  A += z * strA;
  B += z * strB;
  O1 += z * strO1;
  if (O2) O2 += z * strO2;
  int m0 = blockIdx.y * 64, n0 = blockIdx.x * 64;
  __shared__ half_t sA0[64 * 64], sB0[64 * 64];
  __shared__ half_t sA1[64 * 64], sB1[64 * 64];
  int tid = threadIdx.x, lane = tid & 63, wave = tid >> 6;
  int ln15 = lane & 15, quad = lane >> 4;
  int wr = (wave & 1) * 32, wc = (wave >> 1) * 32;
  float4v acc[2][2] = {};
  int KB = K / 64;
  auto compute = [&](const half_t* cA, const half_t* cB) {
    half8 af[2], bf[2];
#pragma unroll
    for (int q = 0; q < 2; ++q) {
#pragma unroll
      for (int i = 0; i < 2; ++i) af[i] = frag64(cA, wr + i * 16 + ln15, q * 4 + quad);
#pragma unroll
      for (int j = 0; j < 2; ++j) bf[j] = frag64(cB, wc + j * 16 + ln15, q * 4 + quad);
#pragma unroll
      for (int i = 0; i < 2; ++i)
#pragma unroll
        for (int j = 0; j < 2; ++j)
          acc[i][j] = __builtin_amdgcn_mfma_f32_16x16x32_f16(af[i], bf[j], acc[i][j], 0, 0, 0);
    }
  };
  stage_rows64(A, m0, ldA, 0, sA0, 512, tid);
  stage_rows64(B, n0, ldB, 0, sB0, 512, tid);
  for (int kb = 0; kb < KB; kb += 2) {
    stage_rows64(A, m0, ldA, (kb + 1) * 64, sA1, 512, tid);
    stage_rows64(B, n0, ldB, (kb + 1) * 64, sB1, 512, tid);
    asm volatile("s_waitcnt vmcnt(4)" ::: "memory");
    __builtin_amdgcn_s_barrier();
    __builtin_amdgcn_sched_barrier(0);
    compute(sA0, sB0);
    __builtin_amdgcn_sched_barrier(0);
    __builtin_amdgcn_s_barrier();
    if (kb + 2 < KB) {
      stage_rows64(A, m0, ldA, (kb + 2) * 64, sA0, 512, tid);
      stage_rows64(B, n0, ldB, (kb + 2) * 64, sB0, 512, tid);
      asm volatile("s_waitcnt vmcnt(4)" ::: "memory");
    } else {
      asm volatile("s_waitcnt vmcnt(0)" ::: "memory");
    }
    __builtin_amdgcn_s_barrier();
    __builtin_amdgcn_sched_barrier(0);
    compute(sA1, sB1);
    __builtin_amdgcn_sched_barrier(0);
    __builtin_amdgcn_s_barrier();
  }
#pragma unroll
  for (int i = 0; i < 2; ++i)
#pragma unroll
    for (int j = 0; j < 2; ++j)
#pragma unroll
      for (int rg = 0; rg < 4; ++rg) {
        int m = m0 + wr + i * 16 + quad * 4 + rg;
        int n = n0 + wc + j * 16 + ln15;
        float v = acc[i][j][rg];
        if (neg) v = -v;
        half_t hv = (half_t)v;
        O1[(size_t)m * ldO1 + n] = hv;
        if (O2) O2[(size_t)n * ldO2 + m] = hv;
      }
}

// ---------------------------------------------------------------------------
extern "C" void kernel_launch(void* const* d_in, const int* in_sizes, int n_in,
                              void* d_out, int out_size, void* d_ws, size_t ws_size,
                              hipStream_t stream) {
  (void)in_sizes; (void)n_in; (void)out_size; (void)ws_size;
  const float* X = (const float*)d_in[0];   // (1792, 8192) fp32
  const float* U = (const float*)d_in[1];   // (1792, 1792) fp32
  float* out = (float*)d_out;               // (1792, 8192) fp32

  char* ws = (char*)d_ws;
  // Slab plan (61.47 MB, verified R10-R13):
  //   [0 .. 29.36M)  XT (written LAST); Tinv aliases its first 6.42MB
  //   [29.36M..35.78M) Vh -> M1T scratch after gram+transpose_h
  //   [35.78M..42.21M) VhT
  //   [42.21M..48.63M) T16
  //   [48.63M..55.05M) WtT
  //   [55.05M..61.47M) TinvT -> Pf after the WtT GEMM
  half_t* Tinv  = (half_t*)(ws);
  half_t* XT    = (half_t*)(ws);
  half_t* Vh    = (half_t*)(ws + 29360128);
  half_t* scr   = Vh;                       // M1T scratch (<= 1.57MB used)
  half_t* VhT   = (half_t*)(ws + 35782656);
  half_t* T16   = (half_t*)(ws + 42205184);
  half_t* WtT   = (half_t*)(ws + 48627712);
  half_t* TinvT = (half_t*)(ws + 55050240);
  half_t* Pf    = TinvT;

  const int D = D_DIM;

  normalize_rows<<<dim3(D), dim3(256), 0, stream>>>(U, Vh);
  // T16 = 2*strict_tril(Vn Vn^T)   (128-tile counted-vmcnt)
  gemm128<0><<<dim3(14, 14), dim3(256), 0, stream>>>(Vh, Vh, T16, D, D, D, D);
  transpose_h<<<dim3(28, 28), dim3(256), 0, stream>>>(Vh, VhT);
  // 14 x 128 diagonal-block inverses -> Tinv/TinvT diag blocks
  diag_inv<<<dim3(448), dim3(256), 0, stream>>>(T16, Tinv, TinvT);
  // zero Tinv strict-upper / TinvT strict-lower blocks
  zero_tri<<<dim3(14, 14), dim3(256), 0, stream>>>(Tinv, TinvT);

  // --- recursive doubling: fill strict-lower blocks of Tinv/TinvT ---
  // L1: 7 pairs of 128 (Aoff=256z, Boff=256z+128)
  {
    long long st = 256LL * D + 256;
    tinv64<<<dim3(2, 2, 7), dim3(256), 0, stream>>>(
        TinvT, D, st, T16 + 128LL * D, D, st, scr, 128, 16384, nullptr, 0, 0, 128, 0);
    tinv64<<<dim3(2, 2, 7), dim3(256), 0, stream>>>(
        scr, 128, 16384, Tinv + 128LL * D + 128, D, st,
        TinvT + 128, D, st, Tinv + 128LL * D, D, st, 128, 1);
  }
  // L2: 3 pairs of 256 (Aoff=512z, Boff=512z+256)
  {
    long long st = 512LL * D + 512;
    tinv64<<<dim3(4, 4, 3), dim3(256), 0, stream>>>(
        TinvT, D, st, T16 + 256LL * D, D, st, scr, 256, 65536, nullptr, 0, 0, 256, 0);
    tinv64<<<dim3(4, 4, 3), dim3(256), 0, stream>>>(
        scr, 256, 65536, Tinv + 256LL * D + 256, D, st,
        TinvT + 256, D, st, Tinv + 256LL * D, D, st, 256, 1);
  }
  // L3a: pair (512@0, 512@512)
  tinv64<<<dim3(8, 8, 1), dim3(256), 0, stream>>>(
      TinvT, D, 0, T16 + 512LL * D, D, 0, scr, 512, 0, nullptr, 0, 0, 512, 0);
  tinv64<<<dim3(8, 8, 1), dim3(256), 0, stream>>>(
      scr, 512, 0, Tinv + 512LL * D + 512, D, 0,
      TinvT + 512, D, 0, Tinv + 512LL * D, D, 0, 512, 1);
  // L3b: pair (512@1024, 256@1536): p=512, q=256
  tinv64<<<dim3(4, 8, 1), dim3(256), 0, stream>>>(
      TinvT + 1024LL * D + 1024, D, 0, T16 + 1536LL * D + 1024, D, 0,
      scr, 256, 0, nullptr, 0, 0, 512, 0);
  tinv64<<<dim3(4, 8, 1), dim3(256), 0, stream>>>(
      scr, 256, 0, Tinv + 1536LL * D + 1536, D, 0,
      TinvT + 1024LL * D + 1536, D, 0, Tinv + 1536LL * D + 1024, D, 0, 256, 1);
  // L4: pair (1024@0, 768@1024): p=1024, q=768
  tinv64<<<dim3(12, 16, 1), dim3(256), 0, stream>>>(
      TinvT, D, 0, T16 + 1024LL * D, D, 0, scr, 768, 0, nullptr, 0, 0, 1024, 0);
  tinv64<<<dim3(12, 16, 1), dim3(256), 0, stream>>>(
      scr, 768, 0, Tinv + 1024LL * D + 1024, D, 0,
      TinvT + 1024, D, 0, Tinv + 1024LL * D, D, 0, 768, 1);

  // WtT[m][r] = 2 * sum_{k<=r} VhT[m][k] * Tinv[r][k]   (triangular K)
  gemm128<3><<<dim3(14, 14), dim3(256), 0, stream>>>(VhT, Tinv, WtT, 0, D, D, D);
  // Tinv now dead -> safe to build XT over its slab
  transpose_x<<<dim3(D / 64, B_DIM / 64), dim3(256), 0, stream>>>(X, XT);
  // Pf = I - Wt^T Vn   (Pf overlays dead TinvT)
  gemm128<1><<<dim3(14, 14), dim3(256), 0, stream>>>(WtT, VhT, Pf, D, D, D, D);
  // out = Pf X   (256^2 / BK=64 / 8-wave counted-vmcnt pipeline)
  gemm_out<<<dim3(224), dim3(512), 0, stream>>>(Pf, XT, out, D, D, D, B_DIM);
}